// Round 2
// baseline (825.303 us; speedup 1.0000x reference)
//
#include <hip/hip_runtime.h>
#include <hip/hip_bf16.h>
#include <stdint.h>

// Problem dims (fixed by reference): B,C,F,W,H,K,S = 64,256,512,64,64,3,1
#define C_DIM 256
#define F_DIM 512
#define B_DIM 64
#define N_DIM 4096          // W*H
#define BM 128
#define BN 128
#define BK 32

typedef __bf16  bf16x8 __attribute__((ext_vector_type(8)));
typedef float   f32x4  __attribute__((ext_vector_type(4)));

// ---------------- prep: W2[f][c] = sum_{3x3} tanh(w + 0.5*log(eps/(1-eps))) ----------------
// tanh(w + 0.5*ln r) = 1 - 2/(e^{2w} r + 1); inf-safe form.
__global__ void prep_w2(const float* __restrict__ w, const float* __restrict__ eps,
                        __hip_bfloat16* __restrict__ w2) {
    int id = blockIdx.x * blockDim.x + threadIdx.x;          // [0, F*C)
    if (id >= F_DIM * C_DIM) return;
    const float* wp = w  + id * 9;
    const float* ep = eps + id * 9;
    float s = 0.f;
#pragma unroll
    for (int i = 0; i < 9; ++i) {
        float wi = wp[i], e = ep[i];
        float r = e / (1.0f - e);
        float t = __expf(2.0f * wi) * r;
        s += 1.0f - 2.0f / (t + 1.0f);
    }
    w2[id] = __float2bfloat16(s);
}

// ---------------- helpers ----------------
__device__ inline void load_lds16(const void* g, void* l) {
    __builtin_amdgcn_global_load_lds(
        (const __attribute__((address_space(1))) uint32_t*)g,
        (__attribute__((address_space(3))) uint32_t*)l, 16, 0, 0);
}

__device__ inline uint32_t pack_bf16x2(float a, float b) {
    union { __hip_bfloat162 h; uint32_t u; } c;
    c.h.x = __float2bfloat16(a);
    c.h.y = __float2bfloat16(b);
    return c.u;
}

// ---------------- pass 1: X[b][c][n] fp32 -> Xt[b][n][c] bf16 ----------------
// Tile: 64 n (lane) x 256 c (full). LDS row stride 520 B: 8-aligned for b64,
// write banks (130*lane + const) mod 32 = 2-way (free), read banks 2-way (free).
__global__ __launch_bounds__(256)
void cvt_transpose(const float* __restrict__ X, __hip_bfloat16* __restrict__ Xt) {
    __shared__ unsigned char s[64 * 520];                    // 33.3 KB
    const int b    = blockIdx.x >> 6;
    const int nt   = blockIdx.x & 63;
    const int lane = threadIdx.x & 63;
    const int wv   = threadIdx.x >> 6;
    const float* Xb = X + (size_t)b * C_DIM * N_DIM + nt * 64;
#pragma unroll 4
    for (int g = 0; g < 16; ++g) {
        int c0 = 4 * wv + 16 * g;                            // 4 consecutive c per thread
        float v0 = Xb[(size_t)(c0 + 0) * N_DIM + lane];      // each load: 256 B coalesced
        float v1 = Xb[(size_t)(c0 + 1) * N_DIM + lane];
        float v2 = Xb[(size_t)(c0 + 2) * N_DIM + lane];
        float v3 = Xb[(size_t)(c0 + 3) * N_DIM + lane];
        uint2 p;
        p.x = pack_bf16x2(v0, v1);
        p.y = pack_bf16x2(v2, v3);
        *(uint2*)(&s[lane * 520 + c0 * 2]) = p;              // b64, 2-way bank = free
    }
    __syncthreads();
    unsigned char* Ob = (unsigned char*)(Xt + ((size_t)b * N_DIM + (size_t)nt * 64) * C_DIM);
#pragma unroll 4
    for (int p = 0; p < 16; ++p) {
        int row = 4 * p + wv;
        uint2 v = *(const uint2*)(&s[row * 520 + lane * 8]);
        *(uint2*)(Ob + (size_t)row * 512 + lane * 8) = v;    // 512 B contiguous per instr
    }
}

// ---------------- pass 2: m97-structure GEMM ----------------
// out[b][f][n] = sum_c W2[f][c] * Xt[b][n][c]; both operands k-contiguous bf16,
// staged via global_load_lds dwordx4 into 64 B rows (2-way conflict frag reads).
__global__ __launch_bounds__(256)
void gemm_kernel(const __hip_bfloat16* __restrict__ Xt,
                 const __hip_bfloat16* __restrict__ W2,
                 float* __restrict__ Out) {
    __shared__ __hip_bfloat16 sA[BM * BK];                 // 8 KB  [f][c]
    __shared__ __hip_bfloat16 sB[BN * BK];                 // 8 KB  [n][c]

    const int tid  = threadIdx.x;
    const int lane = tid & 63;
    const int wave = tid >> 6;

    // XCD-aware swizzle: per-XCD sequence with f-tile fastest -> the 4 blocks
    // sharing an Xt tile land on the same XCD (Xt fetched from HBM once).
    int wid  = (blockIdx.x & 7) * 1024 + (blockIdx.x >> 3);
    int fi   = wid & 3;            // f tile   [0,4)
    int rest = wid >> 2;
    int ni   = rest & 31;          // n tile   [0,32)
    int bi   = rest >> 5;          // batch    [0,64)

    const __hip_bfloat16* Bb = Xt + ((size_t)bi * N_DIM + (size_t)ni * BN) * C_DIM;
    const __hip_bfloat16* Ab = W2 + fi * BM * C_DIM;
    float* Ob                = Out + ((size_t)bi * F_DIM + (size_t)fi * BM) * N_DIM + ni * BN;

    f32x4 acc[4][4];
#pragma unroll
    for (int i = 0; i < 4; ++i)
#pragma unroll
        for (int j = 0; j < 4; ++j)
            acc[i][j] = (f32x4){0.f, 0.f, 0.f, 0.f};

    const int wm  = (wave >> 1) * 64;    // wave tile origin
    const int wn  = (wave & 1) * 64;
    const int l15 = lane & 15;
    const int l4  = lane >> 4;

    for (int kt = 0; kt < C_DIM; kt += BK) {
        __syncthreads();   // previous iter's frag reads done before restaging

#pragma unroll
        for (int j = 0; j < 2; ++j) {
            int slot = j * 256 + tid;            // 16 B slots, lane-contiguous per wave
            int r  = slot >> 2;                  // row [0,128)
            int k8 = slot & 3;                   // 16 B chunk within 64 B row
            char* lp = (char*)sA + (j * 256 + wave * 64) * 16;     // wave-uniform base
            load_lds16((const void*)(Ab + r * C_DIM + kt + k8 * 8), (void*)lp);
            char* lpb = (char*)sB + (j * 256 + wave * 64) * 16;
            load_lds16((const void*)(Bb + r * C_DIM + kt + k8 * 8), (void*)lpb);
        }

        __syncthreads();   // staging complete (barrier drains vmcnt for lds-DMA)

        bf16x8 af[4], bfrag[4];
#pragma unroll
        for (int mi = 0; mi < 4; ++mi) {
            int m = wm + mi * 16 + l15;
            af[mi] = *(const bf16x8*)((const char*)sA + m * 64 + l4 * 16);
        }
#pragma unroll
        for (int nj = 0; nj < 4; ++nj) {
            int n = wn + nj * 16 + l15;
            bfrag[nj] = *(const bf16x8*)((const char*)sB + n * 64 + l4 * 16);
        }
#pragma unroll
        for (int mi = 0; mi < 4; ++mi)
#pragma unroll
            for (int nj = 0; nj < 4; ++nj)
                acc[mi][nj] = __builtin_amdgcn_mfma_f32_16x16x32_bf16(
                    af[mi], bfrag[nj], acc[mi][nj], 0, 0, 0);
    }

    // epilogue: C/D layout col=lane&15, row=(lane>>4)*4+r (m89-verified)
#pragma unroll
    for (int mi = 0; mi < 4; ++mi) {
        int mrow = wm + mi * 16 + l4 * 4;
#pragma unroll
        for (int nj = 0; nj < 4; ++nj) {
            int ncol = wn + nj * 16 + l15;
            float* op = Ob + (size_t)mrow * N_DIM + ncol;
#pragma unroll
            for (int r = 0; r < 4; ++r)
                op[(size_t)r * N_DIM] = acc[mi][nj][r];
        }
    }
}

// ---------------- fallback: R1 fused kernel (if ws too small for Xt) ----------------
#define SB_STRIDE 80
__global__ __launch_bounds__(256)
void gemm_fused(const float* __restrict__ X,
                const __hip_bfloat16* __restrict__ W2,
                float* __restrict__ Out) {
    __shared__ __hip_bfloat16 sA[BM * BK];
    __shared__ unsigned char  sB[BN * SB_STRIDE];
    const int tid  = threadIdx.x;
    const int lane = tid & 63;
    const int wave = tid >> 6;
    int wid  = (blockIdx.x & 7) * 1024 + (blockIdx.x >> 3);
    int fi   = wid & 3;
    int rest = wid >> 2;
    int ni   = rest & 31;
    int bi   = rest >> 5;
    const float* Xb          = X  + (size_t)bi * C_DIM * N_DIM + ni * BN;
    const __hip_bfloat16* Ab = W2 + fi * BM * C_DIM;
    float* Ob                = Out + ((size_t)bi * F_DIM + (size_t)fi * BM) * N_DIM + ni * BN;
    const int bn  = tid & 127;
    const int bkh = tid >> 7;
    f32x4 acc[4][4];
#pragma unroll
    for (int i = 0; i < 4; ++i)
#pragma unroll
        for (int j = 0; j < 4; ++j)
            acc[i][j] = (f32x4){0.f, 0.f, 0.f, 0.f};
    const int wm = (wave >> 1) * 64;
    const int wn = (wave & 1) * 64;
    const int l15 = lane & 15;
    const int l4  = lane >> 4;
    for (int kt = 0; kt < C_DIM; kt += BK) {
        __syncthreads();
#pragma unroll
        for (int j = 0; j < 2; ++j) {
            int slot = j * 256 + tid;
            int m  = slot >> 2;
            int k8 = slot & 3;
            char* lp = (char*)sA + (j * 256 + wave * 64) * 16;
            load_lds16((const void*)(Ab + m * C_DIM + kt + k8 * 8), (void*)lp);
        }
        float xv[4][4];
#pragma unroll
        for (int i = 0; i < 4; ++i) {
            int q  = bkh + 2 * i;
            const float* xp = Xb + (size_t)(kt + 4 * q) * N_DIM + bn;
#pragma unroll
            for (int d = 0; d < 4; ++d) xv[i][d] = xp[(size_t)d * N_DIM];
        }
#pragma unroll
        for (int i = 0; i < 4; ++i) {
            int q = bkh + 2 * i;
            uint2 v;
            v.x = pack_bf16x2(xv[i][0], xv[i][1]);
            v.y = pack_bf16x2(xv[i][2], xv[i][3]);
            *(uint2*)(&sB[bn * SB_STRIDE + q * 8]) = v;
        }
        __syncthreads();
        bf16x8 af[4], bfrag[4];
#pragma unroll
        for (int mi = 0; mi < 4; ++mi) {
            int m = wm + mi * 16 + l15;
            af[mi] = *(const bf16x8*)((const char*)sA + m * 64 + l4 * 16);
        }
#pragma unroll
        for (int nj = 0; nj < 4; ++nj) {
            int n = wn + nj * 16 + l15;
            bfrag[nj] = *(const bf16x8*)(&sB[n * SB_STRIDE + l4 * 16]);
        }
#pragma unroll
        for (int mi = 0; mi < 4; ++mi)
#pragma unroll
            for (int nj = 0; nj < 4; ++nj)
                acc[mi][nj] = __builtin_amdgcn_mfma_f32_16x16x32_bf16(
                    af[mi], bfrag[nj], acc[mi][nj], 0, 0, 0);
    }
#pragma unroll
    for (int mi = 0; mi < 4; ++mi) {
        int mrow = wm + mi * 16 + l4 * 4;
#pragma unroll
        for (int nj = 0; nj < 4; ++nj) {
            int ncol = wn + nj * 16 + l15;
            float* op = Ob + (size_t)mrow * N_DIM + ncol;
#pragma unroll
            for (int r = 0; r < 4; ++r)
                op[(size_t)r * N_DIM] = acc[mi][nj][r];
        }
    }
}

extern "C" void kernel_launch(void* const* d_in, const int* in_sizes, int n_in,
                              void* d_out, int out_size, void* d_ws, size_t ws_size,
                              hipStream_t stream) {
    const float* x   = (const float*)d_in[0];   // [64,256,64,64]
    const float* w   = (const float*)d_in[1];   // [512,256,3,3]
    const float* eps = (const float*)d_in[2];   // [1,512,256,3,3]
    float* out       = (float*)d_out;           // [1,64,512,64,64]

    __hip_bfloat16* w2 = (__hip_bfloat16*)d_ws;                 // 256 KB
    const size_t w2_bytes = (size_t)F_DIM * C_DIM * sizeof(__hip_bfloat16);
    const size_t xt_bytes = (size_t)B_DIM * N_DIM * C_DIM * sizeof(__hip_bfloat16); // 134 MB

    prep_w2<<<dim3((F_DIM * C_DIM + 255) / 256), dim3(256), 0, stream>>>(w, eps, w2);

    if (ws_size >= w2_bytes + xt_bytes) {
        __hip_bfloat16* xt = (__hip_bfloat16*)((char*)d_ws + w2_bytes);
        cvt_transpose<<<dim3(B_DIM * (N_DIM / 64)), dim3(256), 0, stream>>>(x, xt);
        gemm_kernel<<<dim3(8192), dim3(256), 0, stream>>>(xt, w2, out);
    } else {
        gemm_fused<<<dim3(8192), dim3(256), 0, stream>>>(x, w2, out);
    }
}